// Round 7
// baseline (722.685 us; speedup 1.0000x reference)
//
#include <hip/hip_runtime.h>
#include <math.h>

#define NB    1024
#define LI    2
#define LH    256
#define IMG   16
#define PW    24      // padded LDS row stride for v/r planes
#define PH    18
#define NCHL  48      // channels 0..47 live in LDS; 48..63 in named registers

// ---------------------------------------------------------------------------
// prep: collapse h-conv + 1x1 r-conv into one effective 2->1 3x3 conv.
// ---------------------------------------------------------------------------
__global__ void prep_kernel(const float* __restrict__ h_w,
                            const float* __restrict__ h_b,
                            const float* __restrict__ r_w,
                            float* __restrict__ weff) {
    int t = threadIdx.x;
    if (t < 19) {
        float acc = 0.f;
        if (t < 18) {
            for (int c = 0; c < LH; ++c)
                acc += r_w[c] * h_w[c * 18 + t];
        } else {
            for (int c = 0; c < LH; ++c)
                acc += r_w[c] * h_b[c];
        }
        weff[t] = acc;
    }
}

// ---- register-resident channels 48..63 ------------------------------------
#define RLIST(F) \
    F(48,m0) F(49,m1) F(50,m2) F(51,m3) \
    F(52,m0) F(53,m1) F(54,m2) F(55,m3) \
    F(56,m0) F(57,m1) F(58,m2) F(59,m3) \
    F(60,m0) F(61,m1) F(62,m2) F(63,m3)

#define RDECL(c,M) float q##c;
#define RQ(c,M) { float a = q_w[(c)*9+0]*p0; a += q_w[(c)*9+1]*p1;            \
                  a += q_w[(c)*9+2]*p2; a += q_w[(c)*9+3]*p3;                 \
                  a += q_w[(c)*9+4]*p4; a += q_w[(c)*9+5]*p5;                 \
                  a += q_w[(c)*9+6]*p6; a += q_w[(c)*9+7]*p7;                 \
                  a += q_w[(c)*9+8]*p8; q##c = a; M = fmaxf(M, a); }
#define RV(c,M) { float a = q##c;             a += w[(c)*9+0]*p0;             \
                  a += w[(c)*9+1]*p1; a += w[(c)*9+2]*p2;                     \
                  a += w[(c)*9+3]*p3; a += w[(c)*9+4]*p4;                     \
                  a += w[(c)*9+5]*p5; a += w[(c)*9+6]*p6;                     \
                  a += w[(c)*9+7]*p7; a += w[(c)*9+8]*p8;                     \
                  M = fmaxf(M, a); }
// 9 predicated gather-stores of value a for channel c
#define STO9(c,a) { if (gmask & 1)   vout[  0+(c)] = a;                       \
                    if (gmask & 2)   vout[ 64+(c)] = a;                       \
                    if (gmask & 4)   vout[128+(c)] = a;                       \
                    if (gmask & 8)   vout[192+(c)] = a;                       \
                    if (gmask & 16)  vout[256+(c)] = a;                       \
                    if (gmask & 32)  vout[320+(c)] = a;                       \
                    if (gmask & 64)  vout[384+(c)] = a;                       \
                    if (gmask & 128) vout[448+(c)] = a;                       \
                    if (gmask & 256) vout[512+(c)] = a; }
#define RF(c,M) { float a = q##c;             a += w[(c)*9+0]*p0;             \
                  a += w[(c)*9+1]*p1; a += w[(c)*9+2]*p2;                     \
                  a += w[(c)*9+3]*p3; a += w[(c)*9+4]*p4;                     \
                  a += w[(c)*9+5]*p5; a += w[(c)*9+6]*p6;                     \
                  a += w[(c)*9+7]*p7; a += w[(c)*9+8]*p8;                     \
                  STO9(c,a) }

// ---------------------------------------------------------------------------
// main: one block per batch image; 256 threads = 256 pixels (t == px).
// qr: 48 channels in LDS plane [c][px] (stride-1 reads, conflict-free),
//     16 channels in named registers. Per-thread live state ~40 VGPRs.
// ---------------------------------------------------------------------------
__global__ __launch_bounds__(256) void vin_kernel(
    const float* __restrict__ X,     const float* __restrict__ S1,
    const float* __restrict__ S2,    const float* __restrict__ gamma,
    const float* __restrict__ q_w,   const float* __restrict__ w,
    const float* __restrict__ fc1,   const float* __restrict__ fc2,
    const float* __restrict__ fc3,   const float* __restrict__ weff,
    float* __restrict__ out) {
    __shared__ float qlds[NCHL * 256];   // [c][px] : c*256 + px
    __shared__ float rpad[PH * PW];
    __shared__ float vb0[PH * PW];
    __shared__ float vb1[PH * PW];
    __shared__ float vout[580];
    __shared__ float l1[100];
    __shared__ float l2[52];

    const int b = blockIdx.x;
    const int t = threadIdx.x;           // == pixel index
    const int x = t & 15;
    const int y = t >> 4;
    const int tl  = y * PW + x;
    const int ctr = (y + 1) * PW + (x + 1);

    for (int idx = t; idx < PH * PW; idx += 256) {
        rpad[idx] = 0.f;
        vb0[idx]  = 0.f;
        vb1[idx]  = 0.f;
    }
    __syncthreads();

    // ---- r = conv3x3(X, W_eff) + b_eff ----
    const float* Xb = X + (size_t)b * (LI * IMG * IMG);
    float racc = weff[18];
#pragma unroll
    for (int i = 0; i < LI; ++i) {
#pragma unroll
        for (int ky = 0; ky < 3; ++ky) {
            int yy = y + ky - 1;
#pragma unroll
            for (int kx = 0; kx < 3; ++kx) {
                int xx = x + kx - 1;
                if (yy >= 0 && yy < IMG && xx >= 0 && xx < IMG)
                    racc += weff[i * 9 + ky * 3 + kx] * Xb[i * 256 + yy * 16 + xx];
            }
        }
    }
    rpad[ctr] = racc;
    __syncthreads();

    RLIST(RDECL)

    // ---- qr = conv3x3(r, q_w); v0 = max_ch(qr) -> vb0 ----
    {
        float p0 = rpad[tl],        p1 = rpad[tl + 1],        p2 = rpad[tl + 2];
        float p3 = rpad[tl + PW],   p4 = rpad[tl + PW + 1],   p5 = rpad[tl + PW + 2];
        float p6 = rpad[tl + 2*PW], p7 = rpad[tl + 2*PW + 1], p8 = rpad[tl + 2*PW + 2];
        float mL = -1e30f;
#pragma unroll 8
        for (int c = 0; c < NCHL; ++c) {
            float a = q_w[c*9+0]*p0; a += q_w[c*9+1]*p1; a += q_w[c*9+2]*p2;
            a += q_w[c*9+3]*p3; a += q_w[c*9+4]*p4; a += q_w[c*9+5]*p5;
            a += q_w[c*9+6]*p6; a += q_w[c*9+7]*p7; a += q_w[c*9+8]*p8;
            qlds[c * 256 + t] = a;
            mL = fmaxf(mL, a);
        }
        float m0 = mL, m1 = -1e30f, m2 = -1e30f, m3 = -1e30f;
        RLIST(RQ)
        vb0[ctr] = fmaxf(fmaxf(m0, m1), fmaxf(m2, m3));
    }
    __syncthreads();

    // ---- 39 VI steps: v_dst = max_o( qr[o] + conv3x3(v_src, w[o]) ) ----
    float* src = vb0;
    float* dst = vb1;
#pragma unroll 1
    for (int it = 0; it < 39; ++it) {
        float p0 = src[tl],        p1 = src[tl + 1],        p2 = src[tl + 2];
        float p3 = src[tl + PW],   p4 = src[tl + PW + 1],   p5 = src[tl + PW + 2];
        float p6 = src[tl + 2*PW], p7 = src[tl + 2*PW + 1], p8 = src[tl + 2*PW + 2];
        float mL = -1e30f;
#pragma unroll 8
        for (int c = 0; c < NCHL; ++c) {
            float a = qlds[c * 256 + t];
            a += w[c*9+0]*p0; a += w[c*9+1]*p1; a += w[c*9+2]*p2;
            a += w[c*9+3]*p3; a += w[c*9+4]*p4; a += w[c*9+5]*p5;
            a += w[c*9+6]*p6; a += w[c*9+7]*p7; a += w[c*9+8]*p8;
            mL = fmaxf(mL, a);
        }
        float m0 = mL, m1 = -1e30f, m2 = -1e30f, m3 = -1e30f;
        RLIST(RV)
        dst[ctr] = fmaxf(fmaxf(m0, m1), fmaxf(m2, m3));
        __syncthreads();
        float* tmp = src; src = dst; dst = tmp;
    }
    // src now points at the latest v plane.

    // ---- gather mask: which vout slots does this thread's pixel own? ----
    float s1v = S1[b], s2v = S2[b];
    int s1g = (int)floorf(s1v);
    s1g = min(max(s1g, 0), IMG - 1);
    int s2g = IMG - 1 - (int)floorf(s2v);
    s2g = min(max(s2g, 0), IMG - 1);
    int s1i0 = max(s1g - 1, 0), s1i1 = s1g, s1i2 = min(s1g + 1, IMG - 1);
    int s2i0 = max(s2g - 1, 0), s2i1 = s2g, s2i2 = min(s2g + 1, IMG - 1);
    int gmask = 0;
    if (x == s1i0) { if (y == s2i0) gmask |= 1;   if (y == s2i1) gmask |= 2;   if (y == s2i2) gmask |= 4;   }
    if (x == s1i1) { if (y == s2i0) gmask |= 8;   if (y == s2i1) gmask |= 16;  if (y == s2i2) gmask |= 32;  }
    if (x == s1i2) { if (y == s2i0) gmask |= 64;  if (y == s2i1) gmask |= 128; if (y == s2i2) gmask |= 256; }

    // ---- final q = qr + conv3x3(v, w), only on gather threads ----
    if (gmask) {
        float p0 = src[tl],        p1 = src[tl + 1],        p2 = src[tl + 2];
        float p3 = src[tl + PW],   p4 = src[tl + PW + 1],   p5 = src[tl + PW + 2];
        float p6 = src[tl + 2*PW], p7 = src[tl + 2*PW + 1], p8 = src[tl + 2*PW + 2];
#pragma unroll 4
        for (int c = 0; c < NCHL; ++c) {
            float a = qlds[c * 256 + t];
            a += w[c*9+0]*p0; a += w[c*9+1]*p1; a += w[c*9+2]*p2;
            a += w[c*9+3]*p3; a += w[c*9+4]*p4; a += w[c*9+5]*p5;
            a += w[c*9+6]*p6; a += w[c*9+7]*p7; a += w[c*9+8]*p8;
            STO9(c, a)
        }
        float m0, m1, m2, m3;   // unused by RF; keeps macro signature
        (void)m0; (void)m1; (void)m2; (void)m3;
        RLIST(RF)
    }
    if (t == 0) {
        vout[576] = s1v;
        vout[577] = s2v;
        vout[578] = gamma[b];
    }
    __syncthreads();

    // ---- MLP: 579 -> 100 -> 50 -> 1 (summation order preserved) ----
    if (t < 100) {
        float acc = 0.f;
        for (int k2 = 0; k2 < 579; ++k2)
            acc += fc1[t * 579 + k2] * vout[k2];
        l1[t] = fmaxf(acc, 0.f);
    }
    __syncthreads();
    if (t < 50) {
        float acc = 0.f;
        for (int k2 = 0; k2 < 100; ++k2)
            acc += fc2[t * 100 + k2] * l1[k2];
        l2[t] = fmaxf(acc, 0.f);
    }
    __syncthreads();
    if (t == 0) {
        float acc = 0.f;
        for (int k2 = 0; k2 < 50; ++k2)
            acc += fc3[k2] * l2[k2];
        out[b] = acc;
    }
}

extern "C" void kernel_launch(void* const* d_in, const int* in_sizes, int n_in,
                              void* d_out, int out_size, void* d_ws, size_t ws_size,
                              hipStream_t stream) {
    const float* X     = (const float*)d_in[0];
    const float* S1    = (const float*)d_in[1];
    const float* S2    = (const float*)d_in[2];
    const float* gamma = (const float*)d_in[3];
    const float* h_w   = (const float*)d_in[4];
    const float* h_b   = (const float*)d_in[5];
    const float* r_w   = (const float*)d_in[6];
    const float* q_w   = (const float*)d_in[7];
    const float* w     = (const float*)d_in[8];
    const float* fc1   = (const float*)d_in[9];
    const float* fc2   = (const float*)d_in[10];
    const float* fc3   = (const float*)d_in[11];
    float* weff = (float*)d_ws;
    float* outp = (float*)d_out;

    prep_kernel<<<1, 64, 0, stream>>>(h_w, h_b, r_w, weff);
    vin_kernel<<<NB, 256, 0, stream>>>(X, S1, S2, gamma, q_w, w, fc1, fc2, fc3,
                                       weff, outp);
}

// Round 8
// 590.154 us; speedup vs baseline: 1.2246x; 1.2246x over previous
//
#include <hip/hip_runtime.h>
#include <math.h>

#define NB   1024
#define LI   2
#define LH   256
#define KK   40
#define IMG  16
#define PW   24   // padded LDS row stride
#define PH   18

// ---------------------------------------------------------------------------
// prep: collapse h-conv + 1x1 r-conv into one effective 2->1 3x3 conv.
// ---------------------------------------------------------------------------
__global__ void prep_kernel(const float* __restrict__ h_w,
                            const float* __restrict__ h_b,
                            const float* __restrict__ r_w,
                            float* __restrict__ weff) {
    int t = threadIdx.x;
    if (t < 19) {
        float acc = 0.f;
        if (t < 18) {
            for (int c = 0; c < LH; ++c)
                acc += r_w[c] * h_w[c * 18 + t];
        } else {
            for (int c = 0; c < LH; ++c)
                acc += r_w[c] * h_b[c];
        }
        weff[t] = acc;
    }
}

// ---- X-macro channel list: F(channel, max-chain-var) ----------------------
#define CH4(F,a,b,c,d) F(a,m0) F(b,m1) F(c,m2) F(d,m3)
#define CHLIST(F) \
    CH4(F, 0, 1, 2, 3)  CH4(F, 4, 5, 6, 7)  CH4(F, 8, 9,10,11) CH4(F,12,13,14,15) \
    CH4(F,16,17,18,19)  CH4(F,20,21,22,23)  CH4(F,24,25,26,27) CH4(F,28,29,30,31) \
    CH4(F,32,33,34,35)  CH4(F,36,37,38,39)  CH4(F,40,41,42,43) CH4(F,44,45,46,47) \
    CH4(F,48,49,50,51)  CH4(F,52,53,54,55)  CH4(F,56,57,58,59) CH4(F,60,61,62,63)

#define DECL(o,M)  float q##o;
// initial qr = conv3x3(r, q_w); also feed the channel-max chains
#define QCH(o,M)  { float acc = q_w[(o)*9+0]*p0; acc += q_w[(o)*9+1]*p1; \
                    acc += q_w[(o)*9+2]*p2; acc += q_w[(o)*9+3]*p3;      \
                    acc += q_w[(o)*9+4]*p4; acc += q_w[(o)*9+5]*p5;      \
                    acc += q_w[(o)*9+6]*p6; acc += q_w[(o)*9+7]*p7;      \
                    acc += q_w[(o)*9+8]*p8; q##o = acc; M = fmaxf(M, acc); }
// VI step channel: acc = qr + conv3x3(v, w); max-chain only (qr unchanged)
#define VCH(o,M)  { float acc = q##o;            acc += w[(o)*9+0]*p0;   \
                    acc += w[(o)*9+1]*p1; acc += w[(o)*9+2]*p2;          \
                    acc += w[(o)*9+3]*p3; acc += w[(o)*9+4]*p4;          \
                    acc += w[(o)*9+5]*p5; acc += w[(o)*9+6]*p6;          \
                    acc += w[(o)*9+7]*p7; acc += w[(o)*9+8]*p8;          \
                    M = fmaxf(M, acc); }
// 9 predicated gather-stores of value a for channel c
#define STO9(c,a) { if (gmask & 1)   vout[  0+(c)] = a;                  \
                    if (gmask & 2)   vout[ 64+(c)] = a;                  \
                    if (gmask & 4)   vout[128+(c)] = a;                  \
                    if (gmask & 8)   vout[192+(c)] = a;                  \
                    if (gmask & 16)  vout[256+(c)] = a;                  \
                    if (gmask & 32)  vout[320+(c)] = a;                  \
                    if (gmask & 64)  vout[384+(c)] = a;                  \
                    if (gmask & 128) vout[448+(c)] = a;                  \
                    if (gmask & 256) vout[512+(c)] = a; }
// final q = qr + conv3x3(v, w), stored straight to gather slots
#define FCH(o,M)  { float acc = q##o;            acc += w[(o)*9+0]*p0;   \
                    acc += w[(o)*9+1]*p1; acc += w[(o)*9+2]*p2;          \
                    acc += w[(o)*9+3]*p3; acc += w[(o)*9+4]*p4;          \
                    acc += w[(o)*9+5]*p5; acc += w[(o)*9+6]*p6;          \
                    acc += w[(o)*9+7]*p7; acc += w[(o)*9+8]*p8;          \
                    STO9(o, acc) }

// one VI step: v_DST = max_o( qr[o] + conv3x3(v_SRC, w[o]) )
#define STEP(SRC, DST)                                                        \
    do {                                                                      \
        float p0 = SRC[tl],        p1 = SRC[tl + 1],        p2 = SRC[tl + 2]; \
        float p3 = SRC[tl + PW],   p4 = SRC[tl + PW + 1],   p5 = SRC[tl + PW + 2]; \
        float p6 = SRC[tl + 2*PW], p7 = SRC[tl + 2*PW + 1], p8 = SRC[tl + 2*PW + 2]; \
        float m0 = -1e30f, m1 = -1e30f, m2 = -1e30f, m3 = -1e30f;             \
        CHLIST(VCH)                                                           \
        DST[ctr] = fmaxf(fmaxf(m0, m1), fmaxf(m2, m3));                       \
        __syncthreads();                                                      \
    } while (0)

// ---------------------------------------------------------------------------
// main: one block per batch image; 256 threads = 16x16 pixels.
// qr in 64 NAMED scalar registers. Plain launch_bounds(256): the ",2"
// variant capped regalloc at 68 VGPRs and forced spills (r4/r5 evidence);
// without it the backend allocated 104+ (r7 evidence).
// ---------------------------------------------------------------------------
__global__ __launch_bounds__(256) void vin_kernel(
    const float* __restrict__ X,     const float* __restrict__ S1,
    const float* __restrict__ S2,    const float* __restrict__ gamma,
    const float* __restrict__ q_w,   const float* __restrict__ w,
    const float* __restrict__ fc1,   const float* __restrict__ fc2,
    const float* __restrict__ fc3,   const float* __restrict__ weff,
    float* __restrict__ out) {
    __shared__ float rpad[PH * PW];
    __shared__ float vb0[PH * PW];
    __shared__ float vb1[PH * PW];
    __shared__ float vout[580];
    __shared__ float l1[100];
    __shared__ float l2[52];

    const int b = blockIdx.x;
    const int t = threadIdx.x;
    const int x = t & 15;
    const int y = t >> 4;
    const int tl  = y * PW + x;
    const int ctr = (y + 1) * PW + (x + 1);

    for (int idx = t; idx < PH * PW; idx += 256) {
        rpad[idx] = 0.f;
        vb0[idx]  = 0.f;
        vb1[idx]  = 0.f;
    }
    __syncthreads();

    // ---- r = conv3x3(X, W_eff) + b_eff ----
    const float* Xb = X + (size_t)b * (LI * IMG * IMG);
    float racc = weff[18];
#pragma unroll
    for (int i = 0; i < LI; ++i) {
#pragma unroll
        for (int ky = 0; ky < 3; ++ky) {
            int yy = y + ky - 1;
#pragma unroll
            for (int kx = 0; kx < 3; ++kx) {
                int xx = x + kx - 1;
                if (yy >= 0 && yy < IMG && xx >= 0 && xx < IMG)
                    racc += weff[i * 9 + ky * 3 + kx] * Xb[i * 256 + yy * 16 + xx];
            }
        }
    }
    rpad[ctr] = racc;
    __syncthreads();

    CHLIST(DECL)

    // ---- qr = conv3x3(r, q_w); v0 = max_ch(qr) ----
    {
        float p0 = rpad[tl],        p1 = rpad[tl + 1],        p2 = rpad[tl + 2];
        float p3 = rpad[tl + PW],   p4 = rpad[tl + PW + 1],   p5 = rpad[tl + PW + 2];
        float p6 = rpad[tl + 2*PW], p7 = rpad[tl + 2*PW + 1], p8 = rpad[tl + 2*PW + 2];
        float m0 = -1e30f, m1 = -1e30f, m2 = -1e30f, m3 = -1e30f;
        CHLIST(QCH)
        vb0[ctr] = fmaxf(fmaxf(m0, m1), fmaxf(m2, m3));
    }
    __syncthreads();

    // ---- 39 VI steps (19 double-steps + 1); keep outer loop rolled ----
#pragma unroll 1
    for (int i = 0; i < 19; ++i) {
        STEP(vb0, vb1);
        STEP(vb1, vb0);
    }
    STEP(vb0, vb1);   // latest v now in vb1

    // ---- gather mask: which vout slots does this thread's pixel own? ----
    float s1v = S1[b], s2v = S2[b];
    int s1g = (int)floorf(s1v);
    s1g = min(max(s1g, 0), IMG - 1);
    int s2g = IMG - 1 - (int)floorf(s2v);
    s2g = min(max(s2g, 0), IMG - 1);
    int s1i0 = max(s1g - 1, 0), s1i1 = s1g, s1i2 = min(s1g + 1, IMG - 1);
    int s2i0 = max(s2g - 1, 0), s2i1 = s2g, s2i2 = min(s2g + 1, IMG - 1);
    int gmask = 0;
    if (x == s1i0) { if (y == s2i0) gmask |= 1;   if (y == s2i1) gmask |= 2;   if (y == s2i2) gmask |= 4;   }
    if (x == s1i1) { if (y == s2i0) gmask |= 8;   if (y == s2i1) gmask |= 16;  if (y == s2i2) gmask |= 32;  }
    if (x == s1i2) { if (y == s2i0) gmask |= 64;  if (y == s2i1) gmask |= 128; if (y == s2i2) gmask |= 256; }

    // ---- final q = qr + conv3x3(v, w), only on gather threads ----
    if (gmask) {
        float p0 = vb1[tl],        p1 = vb1[tl + 1],        p2 = vb1[tl + 2];
        float p3 = vb1[tl + PW],   p4 = vb1[tl + PW + 1],   p5 = vb1[tl + PW + 2];
        float p6 = vb1[tl + 2*PW], p7 = vb1[tl + 2*PW + 1], p8 = vb1[tl + 2*PW + 2];
        CHLIST(FCH)
    }
    if (t == 0) {
        vout[576] = s1v;
        vout[577] = s2v;
        vout[578] = gamma[b];
    }
    __syncthreads();

    // ---- MLP: 579 -> 100 -> 50 -> 1 ----
    if (t < 100) {
        float acc = 0.f;
        for (int k2 = 0; k2 < 579; ++k2)
            acc += fc1[t * 579 + k2] * vout[k2];
        l1[t] = fmaxf(acc, 0.f);
    }
    __syncthreads();
    if (t < 50) {
        float acc = 0.f;
        for (int k2 = 0; k2 < 100; ++k2)
            acc += fc2[t * 100 + k2] * l1[k2];
        l2[t] = fmaxf(acc, 0.f);
    }
    __syncthreads();
    if (t == 0) {
        float acc = 0.f;
        for (int k2 = 0; k2 < 50; ++k2)
            acc += fc3[k2] * l2[k2];
        out[b] = acc;
    }
}

extern "C" void kernel_launch(void* const* d_in, const int* in_sizes, int n_in,
                              void* d_out, int out_size, void* d_ws, size_t ws_size,
                              hipStream_t stream) {
    const float* X     = (const float*)d_in[0];
    const float* S1    = (const float*)d_in[1];
    const float* S2    = (const float*)d_in[2];
    const float* gamma = (const float*)d_in[3];
    const float* h_w   = (const float*)d_in[4];
    const float* h_b   = (const float*)d_in[5];
    const float* r_w   = (const float*)d_in[6];
    const float* q_w   = (const float*)d_in[7];
    const float* w     = (const float*)d_in[8];
    const float* fc1   = (const float*)d_in[9];
    const float* fc2   = (const float*)d_in[10];
    const float* fc3   = (const float*)d_in[11];
    float* weff = (float*)d_ws;
    float* outp = (float*)d_out;

    prep_kernel<<<1, 64, 0, stream>>>(h_w, h_b, r_w, weff);
    vin_kernel<<<NB, 256, 0, stream>>>(X, S1, S2, gamma, q_w, w, fc1, fc2, fc3,
                                       weff, outp);
}